// Round 5
// baseline (399.766 us; speedup 1.0000x reference)
//
#include <hip/hip_runtime.h>
#include <hip/hip_fp16.h>
#include <math.h>

// Problem constants (x: [32,64,64,64] f32, embedding: [64,1024] f32)
#define NPIX   131072
#define DDIM   64
#define KCODE  1024
#define BETA   0.25f
#define EPS2   4e-3f      // top-2 gap threshold triggering exact fp32 fix-up
#define FIXCAP 2048

// d_out layout (float32), in reference return order:
#define Q_OFF    0
#define LOSS_OFF 8388608
#define PERP_OFF 8388609
#define ENC_OFF  8388610   // NOTE: byte base ≡ 8 (mod 16) -> enc+2 is 16B-aligned
#define IDX_OFF  142606338

// scratch parked inside the enc region (float offsets from enc base); all of
// it is overwritten by vq_fill afterwards. Offsets chosen so these regions
// land 16B-aligned (enc base byte ≡ 8 mod 16).
#define EHT_F      4194306    // f16[1024][64] hi
#define ELT_F      4227078    // f16[1024][64] lo
#define FIXLIST_I  4259848    // int[FIXCAP]
#define FIXCOUNT_I 4261896    // int

// ws layout (bytes):
//   [0,32768) loss partials f32[8192]; [32768,36864) hist int[1024];
//   [36864,40960) norms f32[1024];     [40960,303104) embT f32[1024][64]

typedef _Float16 half8 __attribute__((ext_vector_type(8)));
typedef float    f32x4 __attribute__((ext_vector_type(4)));

// ---------- prep: transpose to embT, f16 hi/lo split ----------
__global__ void vq_prep(const float* __restrict__ emb, float* __restrict__ embT,
                        __half* __restrict__ eh, __half* __restrict__ el) {
    int i = blockIdx.x * 256 + threadIdx.x;   // over 65536
    int d = i >> 10;
    int k = i & 1023;
    float v = emb[i];
    embT[k * DDIM + d] = v;
    _Float16 h = (_Float16)v;
    _Float16 l = (_Float16)(v - (float)h);
    ((_Float16*)eh)[k * DDIM + d] = h;
    ((_Float16*)el)[k * DDIM + d] = l;
}

__global__ void vq_norms(const float* __restrict__ emb, float* __restrict__ norms) {
    int k = blockIdx.x * 256 + threadIdx.x;   // over 1024
    float s = 0.f;
    #pragma unroll 8
    for (int d = 0; d < DDIM; ++d) {
        float v = emb[d * KCODE + k];
        s = fmaf(v, v, s);
    }
    norms[k] = s;
}

// ---------- MFMA argmin: block = 4 waves x 32 pixels; ALL 1024 codes ----------
// 8 K-panels of 128 codes staged to LDS inside the block (x read ONCE).
// dist = ||e||^2 - 2 x.e. dot via 3 f16-split MFMAs. Global top-2 per pixel;
// gap < EPS2 -> exact fp32 fix-up later. Writes idxf directly.
__global__ __launch_bounds__(256) void vq_argmin_mfma(
        const float* __restrict__ x, const __half* __restrict__ eh,
        const __half* __restrict__ el, const float* __restrict__ norms,
        float* __restrict__ idxf, int* __restrict__ fixlist,
        int* __restrict__ fixcount) {
    __shared__ char lds_raw[33280];
    half8* EH8 = (half8*)lds_raw;              // [128 codes][8 granules] swizzled
    half8* EL8 = (half8*)(lds_raw + 16384);
    float* NRM = (float*)(lds_raw + 32768);    // [128]

    const int tid  = threadIdx.x;
    const int wave = tid >> 6;
    const int lane = tid & 63;
    const int lx = lane & 15;   // B col / A row
    const int lk = lane >> 4;   // k-group
    const int pixbase = blockIdx.x * 128 + wave * 32;

    // A fragments (x rows) -> registers once, reused for all 1024 codes.
    half8 ah[2][2], al[2][2];
    #pragma unroll
    for (int mt = 0; mt < 2; ++mt) {
        const float* xr = x + (size_t)(pixbase + mt * 16 + lx) * DDIM + lk * 8;
        #pragma unroll
        for (int kh = 0; kh < 2; ++kh) {
            float4 v0 = *(const float4*)(xr + kh * 32);
            float4 v1 = *(const float4*)(xr + kh * 32 + 4);
            half8 hh, ll;
            float vv;
            vv = v0.x; hh[0] = (_Float16)vv; ll[0] = (_Float16)(vv - (float)hh[0]);
            vv = v0.y; hh[1] = (_Float16)vv; ll[1] = (_Float16)(vv - (float)hh[1]);
            vv = v0.z; hh[2] = (_Float16)vv; ll[2] = (_Float16)(vv - (float)hh[2]);
            vv = v0.w; hh[3] = (_Float16)vv; ll[3] = (_Float16)(vv - (float)hh[3]);
            vv = v1.x; hh[4] = (_Float16)vv; ll[4] = (_Float16)(vv - (float)hh[4]);
            vv = v1.y; hh[5] = (_Float16)vv; ll[5] = (_Float16)(vv - (float)hh[5]);
            vv = v1.z; hh[6] = (_Float16)vv; ll[6] = (_Float16)(vv - (float)hh[6]);
            vv = v1.w; hh[7] = (_Float16)vv; ll[7] = (_Float16)(vv - (float)hh[7]);
            ah[mt][kh] = hh;
            al[mt][kh] = ll;
        }
    }

    // running top-2 per slot (mt, r): pixel p_local = mt*16 + lk*4 + r
    float b1[2][4], b2[2][4];
    int   i1[2][4];
    #pragma unroll
    for (int mt = 0; mt < 2; ++mt)
        #pragma unroll
        for (int r = 0; r < 4; ++r) { b1[mt][r] = 3.4e38f; b2[mt][r] = 3.4e38f; i1[mt][r] = 0; }

    #pragma unroll 1
    for (int t = 0; t < 8; ++t) {
        const int kbase = t * 128;
        __syncthreads();   // previous panel fully consumed
        {
            const float4* sh = (const float4*)(eh + (size_t)kbase * DDIM);
            const float4* sl = (const float4*)(el + (size_t)kbase * DDIM);
            float4* dh = (float4*)EH8;
            float4* dl = (float4*)EL8;
            #pragma unroll
            for (int i = 0; i < 4; ++i) {
                int G = tid + i * 256;            // 0..1023 granules of 16B
                int code = G >> 3, g = G & 7;
                int sw = g ^ (code & 7);          // XOR granule swizzle
                dh[code * 8 + sw] = sh[G];
                dl[code * 8 + sw] = sl[G];
            }
            if (tid < 128) NRM[tid] = norms[kbase + tid];
        }
        __syncthreads();

        #pragma unroll 1
        for (int c = 0; c < 8; ++c) {
            int code = c * 16 + lx;
            const half8* bh = EH8 + code * 8;
            const half8* bl = EL8 + code * 8;
            int sw0 = lk ^ (code & 7);
            int sw1 = (lk + 4) ^ (code & 7);
            half8 bh0 = bh[sw0], bh1 = bh[sw1];
            half8 bl0 = bl[sw0], bl1 = bl[sw1];

            f32x4 acc0 = {0.f, 0.f, 0.f, 0.f};
            f32x4 acc1 = {0.f, 0.f, 0.f, 0.f};
            acc0 = __builtin_amdgcn_mfma_f32_16x16x32_f16(ah[0][0], bh0, acc0, 0, 0, 0);
            acc1 = __builtin_amdgcn_mfma_f32_16x16x32_f16(ah[1][0], bh0, acc1, 0, 0, 0);
            acc0 = __builtin_amdgcn_mfma_f32_16x16x32_f16(ah[0][1], bh1, acc0, 0, 0, 0);
            acc1 = __builtin_amdgcn_mfma_f32_16x16x32_f16(ah[1][1], bh1, acc1, 0, 0, 0);
            acc0 = __builtin_amdgcn_mfma_f32_16x16x32_f16(ah[0][0], bl0, acc0, 0, 0, 0);
            acc1 = __builtin_amdgcn_mfma_f32_16x16x32_f16(ah[1][0], bl0, acc1, 0, 0, 0);
            acc0 = __builtin_amdgcn_mfma_f32_16x16x32_f16(ah[0][1], bl1, acc0, 0, 0, 0);
            acc1 = __builtin_amdgcn_mfma_f32_16x16x32_f16(ah[1][1], bl1, acc1, 0, 0, 0);
            acc0 = __builtin_amdgcn_mfma_f32_16x16x32_f16(al[0][0], bh0, acc0, 0, 0, 0);
            acc1 = __builtin_amdgcn_mfma_f32_16x16x32_f16(al[1][0], bh0, acc1, 0, 0, 0);
            acc0 = __builtin_amdgcn_mfma_f32_16x16x32_f16(al[0][1], bh1, acc0, 0, 0, 0);
            acc1 = __builtin_amdgcn_mfma_f32_16x16x32_f16(al[1][1], bh1, acc1, 0, 0, 0);

            float nrm = NRM[c * 16 + lx];
            int codeg = kbase + c * 16 + lx;
            #pragma unroll
            for (int r = 0; r < 4; ++r) {
                // C layout [m89]: col = lane&15 (code), row = (lane>>4)*4 + r (pixel)
                float d0 = fmaf(-2.0f, acc0[r], nrm);
                bool lt0 = d0 < b1[0][r];
                b2[0][r] = fminf(b2[0][r], fmaxf(b1[0][r], d0));
                b1[0][r] = fminf(b1[0][r], d0);
                i1[0][r] = lt0 ? codeg : i1[0][r];
                float d1 = fmaf(-2.0f, acc1[r], nrm);
                bool lt1 = d1 < b1[1][r];
                b2[1][r] = fminf(b2[1][r], fmaxf(b1[1][r], d1));
                b1[1][r] = fminf(b1[1][r], d1);
                i1[1][r] = lt1 ? codeg : i1[1][r];
            }
        }
    }

    // cross-lane per-pixel top-2 merge via LDS scratch (panels now dead)
    __syncthreads();
    float* S  = (float*)(lds_raw + wave * 6528);  // 3 planes of [32][17] floats
    float* SB1 = S, *SI = S + 544, *SB2 = S + 1088;
    #pragma unroll
    for (int mt = 0; mt < 2; ++mt)
        #pragma unroll
        for (int r = 0; r < 4; ++r) {
            int p = mt * 16 + lk * 4 + r;
            SB1[p * 17 + lx] = b1[mt][r];
            SI [p * 17 + lx] = (float)i1[mt][r];
            SB2[p * 17 + lx] = b2[mt][r];
        }
    __syncthreads();

    if (lane < 32) {
        float gb1 = 3.4e38f, gb2 = 3.4e38f;
        int gi1 = KCODE;
        #pragma unroll
        for (int j = 0; j < 16; ++j) {
            float cb1 = SB1[lane * 17 + j];
            int   ci1 = (int)SI[lane * 17 + j];
            float cb2 = SB2[lane * 17 + j];
            if (cb1 < gb1 || (cb1 == gb1 && ci1 < gi1)) {
                gb2 = fminf(gb1, cb2); gb1 = cb1; gi1 = ci1;
            } else {
                gb2 = fminf(gb2, cb1);
            }
        }
        int pixel = pixbase + lane;
        idxf[pixel] = (float)gi1;
        if (gb2 - gb1 < EPS2) {
            int slot = atomicAdd(fixcount, 1);
            if (slot < FIXCAP) fixlist[slot] = pixel;
        }
    }
}

// ---------- exact fp32 rescan for flagged pixels (first-min-wins) ----------
__global__ __launch_bounds__(64) void vq_fixup(
        const float* __restrict__ x, const float* __restrict__ embT,
        const float* __restrict__ norms, const int* __restrict__ fixlist,
        const int* __restrict__ fixcount, float* __restrict__ idxf) {
    int b = blockIdx.x;
    int cnt = *fixcount;
    if (b >= cnt) return;
    int pixel = fixlist[b];
    int lane = threadIdx.x;

    float xr[64];
    const float4* x4 = (const float4*)(x + (size_t)pixel * DDIM);
    #pragma unroll
    for (int j = 0; j < 16; ++j) {
        float4 v = x4[j];
        xr[j * 4] = v.x; xr[j * 4 + 1] = v.y; xr[j * 4 + 2] = v.z; xr[j * 4 + 3] = v.w;
    }
    float bd = 3.4e38f;
    int bi = 0;
    #pragma unroll 1
    for (int c = 0; c < 16; ++c) {
        int k = lane * 16 + c;               // per-lane ascending idx
        const float4* e4 = (const float4*)(embT + (size_t)k * DDIM);
        float a0 = 0.f, a1 = 0.f, a2 = 0.f, a3 = 0.f;
        #pragma unroll
        for (int j = 0; j < 16; ++j) {
            float4 ev = e4[j];
            a0 = fmaf(xr[j * 4],     ev.x, a0);
            a1 = fmaf(xr[j * 4 + 1], ev.y, a1);
            a2 = fmaf(xr[j * 4 + 2], ev.z, a2);
            a3 = fmaf(xr[j * 4 + 3], ev.w, a3);
        }
        float dd = fmaf(-2.0f, (a0 + a1) + (a2 + a3), norms[k]);
        if (dd < bd) { bd = dd; bi = k; }
    }
    #pragma unroll
    for (int m = 1; m < 64; m <<= 1) {       // lex-min (dist, idx) across 64 lanes
        float od = __shfl_xor(bd, m, 64);
        int   oi = __shfl_xor(bi, m, 64);
        if (od < bd || (od == bd && oi < bi)) { bd = od; bi = oi; }
    }
    if (lane == 0) idxf[pixel] = (float)bi;
}

// ---------- gather quantized + per-block loss partials + histogram ----------
__global__ __launch_bounds__(256) void vq_gather_loss(
        const float* __restrict__ x, const float* __restrict__ embT,
        const float* __restrict__ idxf, float* __restrict__ q,
        float* __restrict__ lossp, int* __restrict__ hist) {
    __shared__ float red[256];
    int i = blockIdx.x * 256 + threadIdx.x;   // over 2097152 float4 units
    int n = i >> 4;
    int j = i & 15;
    int idx = (int)idxf[n];
    if (j == 0) atomicAdd(&hist[idx], 1);
    float4 e4 = ((const float4*)embT)[idx * 16 + j];
    float4 xv = ((const float4*)x)[i];
    ((float4*)q)[i] = e4;
    float dx = e4.x - xv.x, dy = e4.y - xv.y, dz = e4.z - xv.z, dw = e4.w - xv.w;
    red[threadIdx.x] = dx*dx + dy*dy + dz*dz + dw*dw;
    __syncthreads();
    for (int st = 128; st > 0; st >>= 1) {
        if (threadIdx.x < st) red[threadIdx.x] += red[threadIdx.x + st];
        __syncthreads();
    }
    if (threadIdx.x == 0) lossp[blockIdx.x] = red[0];
}

// ---------- one-hot fill: flat 16B-aligned nontemporal stream ----------
// enc base byte ≡ 8 (mod 16) -> enc+2 is 16B aligned. Head/tail 2 floats
// handled by thread 0. Aligned float4 segments: 33554431.
__global__ __launch_bounds__(256) void vq_fill(const float* __restrict__ idxf,
                                               float* __restrict__ enc) {
    const long long NSEG = 33554431LL;
    f32x4* base = (f32x4*)(enc + 2);
    long long t0 = (long long)blockIdx.x * 256 + threadIdx.x;
    long long stride = (long long)gridDim.x * 256;
    for (long long s = t0; s < NSEG; s += stride) {
        long long f = 2 + 4 * s;              // flat float index into enc
        int n = (int)(f >> 10);
        int k = (int)(f & 1023);
        int idx0 = (int)idxf[n];
        f32x4 v;
        if (k <= 1020) {
            v.x = (k     == idx0) ? 1.f : 0.f;
            v.y = (k + 1 == idx0) ? 1.f : 0.f;
            v.z = (k + 2 == idx0) ? 1.f : 0.f;
            v.w = (k + 3 == idx0) ? 1.f : 0.f;
        } else {                              // k == 1022: crosses row boundary
            int idx1 = (int)idxf[n + 1];
            v.x = (1022 == idx0) ? 1.f : 0.f;
            v.y = (1023 == idx0) ? 1.f : 0.f;
            v.z = (0    == idx1) ? 1.f : 0.f;
            v.w = (1    == idx1) ? 1.f : 0.f;
        }
        __builtin_nontemporal_store(v, &base[s]);
    }
    if (t0 == 0) {
        int idx0 = (int)idxf[0];
        enc[0] = (idx0 == 0) ? 1.f : 0.f;
        enc[1] = (idx0 == 1) ? 1.f : 0.f;
        int idxL = (int)idxf[NPIX - 1];
        enc[134217726] = (idxL == 1022) ? 1.f : 0.f;
        enc[134217727] = (idxL == 1023) ? 1.f : 0.f;
    }
}

// ---------- finalize: loss sum + perplexity ----------
__global__ void vq_final(const float* __restrict__ lossp, const int* __restrict__ hist,
                         float* __restrict__ out_loss, float* __restrict__ out_perp) {
    __shared__ double red[256];
    int tid = threadIdx.x;
    double s = 0.0;
    for (int i = tid; i < 8192; i += 256) s += (double)lossp[i];
    red[tid] = s;
    __syncthreads();
    for (int st = 128; st > 0; st >>= 1) {
        if (tid < st) red[tid] += red[tid + st];
        __syncthreads();
    }
    if (tid == 0)
        *out_loss = (float)((double)BETA * red[0] / (double)((size_t)NPIX * DDIM));
    __syncthreads();

    double e = 0.0;
    for (int i = tid; i < KCODE; i += 256) {
        float p = (float)hist[i] / (float)NPIX;
        e += (double)(p * logf(p + 1e-10f));
    }
    red[tid] = e;
    __syncthreads();
    for (int st = 128; st > 0; st >>= 1) {
        if (tid < st) red[tid] += red[tid + st];
        __syncthreads();
    }
    if (tid == 0) *out_perp = expf((float)(-red[0]));
}

extern "C" void kernel_launch(void* const* d_in, const int* in_sizes, int n_in,
                              void* d_out, int out_size, void* d_ws, size_t ws_size,
                              hipStream_t stream) {
    const float* x   = (const float*)d_in[0];
    const float* emb = (const float*)d_in[1];
    float* out = (float*)d_out;

    char* ws = (char*)d_ws;
    float* lossp = (float*)ws;              // 8192 floats
    int*   hist  = (int*)(ws + 32768);      // 1024 ints
    float* norms = (float*)(ws + 36864);    // 1024 floats
    float* embT  = (float*)(ws + 40960);    // 65536 floats

    float* q      = out + Q_OFF;
    float* o_loss = out + LOSS_OFF;
    float* o_perp = out + PERP_OFF;
    float* enc    = out + ENC_OFF;
    float* idxf   = out + IDX_OFF;

    // scratch inside the enc region (fully overwritten by vq_fill afterwards)
    __half* eh    = (__half*)(enc + EHT_F);
    __half* el    = (__half*)(enc + ELT_F);
    int* fixlist  = (int*)(enc + FIXLIST_I);
    int* fixcount = (int*)(enc + FIXCOUNT_I);

    (void)hipMemsetAsync(ws + 32768, 0, 4096, stream);          // hist
    (void)hipMemsetAsync((void*)fixcount, 0, 4, stream);        // fix-up counter

    vq_prep<<<256, 256, 0, stream>>>(emb, embT, eh, el);
    vq_norms<<<4, 256, 0, stream>>>(emb, norms);
    vq_argmin_mfma<<<NPIX / 128, 256, 0, stream>>>(x, eh, el, norms, idxf,
                                                   fixlist, fixcount);
    vq_fixup<<<FIXCAP, 64, 0, stream>>>(x, embT, norms, fixlist, fixcount, idxf);
    vq_gather_loss<<<8192, 256, 0, stream>>>(x, embT, idxf, q, lossp, hist);
    vq_fill<<<4096, 256, 0, stream>>>(idxf, enc);
    vq_final<<<1, 256, 0, stream>>>(lossp, hist, o_loss, o_perp);
}

// Round 6
// 379.952 us; speedup vs baseline: 1.0521x; 1.0521x over previous
//
#include <hip/hip_runtime.h>
#include <hip/hip_fp16.h>
#include <math.h>

// Problem constants (x: [32,64,64,64] f32, embedding: [64,1024] f32)
#define NPIX   131072
#define DDIM   64
#define KCODE  1024
#define BETA   0.25f
#define EPS2   4e-3f      // top-2 gap threshold triggering exact fp32 fix-up
#define FIXCAP 2048

// d_out layout (float32), in reference return order:
#define Q_OFF    0
#define LOSS_OFF 8388608
#define PERP_OFF 8388609
#define ENC_OFF  8388610   // NOTE: byte base ≡ 8 (mod 16) -> enc+2 is 16B-aligned
#define IDX_OFF  142606338

// scratch parked inside the enc region (float offsets from enc base); all of
// it is overwritten by vq_fill afterwards. Offsets chosen so these regions
// land 16B-aligned (enc base byte ≡ 8 mod 16).
#define EHT_F      4194306    // f16[1024][64] hi
#define ELT_F      4227078    // f16[1024][64] lo
#define FIXLIST_I  4259848    // int[FIXCAP]
#define FIXCOUNT_I 4261896    // int

// ws layout (bytes):
//   [0,32768) loss partials f32[8192]; [32768,36864) hist int[1024];
//   [36864,40960) norms f32[1024];     [40960,303104) embT f32[1024][64]

typedef _Float16 half8 __attribute__((ext_vector_type(8)));
typedef float    f32x4 __attribute__((ext_vector_type(4)));

// ---------- prep: transpose to embT, f16 hi/lo split ----------
__global__ void vq_prep(const float* __restrict__ emb, float* __restrict__ embT,
                        __half* __restrict__ eh, __half* __restrict__ el) {
    int i = blockIdx.x * 256 + threadIdx.x;   // over 65536
    int d = i >> 10;
    int k = i & 1023;
    float v = emb[i];
    embT[k * DDIM + d] = v;
    _Float16 h = (_Float16)v;
    _Float16 l = (_Float16)(v - (float)h);
    ((_Float16*)eh)[k * DDIM + d] = h;
    ((_Float16*)el)[k * DDIM + d] = l;
}

__global__ void vq_norms(const float* __restrict__ emb, float* __restrict__ norms) {
    int k = blockIdx.x * 256 + threadIdx.x;   // over 1024
    float s = 0.f;
    #pragma unroll 8
    for (int d = 0; d < DDIM; ++d) {
        float v = emb[d * KCODE + k];
        s = fmaf(v, v, s);
    }
    norms[k] = s;
}

// ---------- MFMA argmin: block = 4 waves x 32 pixels; ALL 1024 codes ----------
// 8 K-panels of 128 codes staged to LDS inside the block (x read ONCE).
// dist = ||e||^2 - 2 x.e. dot via 3 f16-split MFMAs. Global top-2 per pixel;
// gap < EPS2 -> exact fp32 fix-up later. Writes idxf directly.
__global__ __launch_bounds__(256) void vq_argmin_mfma(
        const float* __restrict__ x, const __half* __restrict__ eh,
        const __half* __restrict__ el, const float* __restrict__ norms,
        float* __restrict__ idxf, int* __restrict__ fixlist,
        int* __restrict__ fixcount) {
    __shared__ char lds_raw[33280];
    half8* EH8 = (half8*)lds_raw;              // [128 codes][8 granules] swizzled
    half8* EL8 = (half8*)(lds_raw + 16384);
    float* NRM = (float*)(lds_raw + 32768);    // [128]

    const int tid  = threadIdx.x;
    const int wave = tid >> 6;
    const int lane = tid & 63;
    const int lx = lane & 15;   // B col / A row
    const int lk = lane >> 4;   // k-group
    const int pixbase = blockIdx.x * 128 + wave * 32;

    // A fragments (x rows) -> registers once, reused for all 1024 codes.
    half8 ah[2][2], al[2][2];
    #pragma unroll
    for (int mt = 0; mt < 2; ++mt) {
        const float* xr = x + (size_t)(pixbase + mt * 16 + lx) * DDIM + lk * 8;
        #pragma unroll
        for (int kh = 0; kh < 2; ++kh) {
            float4 v0 = *(const float4*)(xr + kh * 32);
            float4 v1 = *(const float4*)(xr + kh * 32 + 4);
            half8 hh, ll;
            float vv;
            vv = v0.x; hh[0] = (_Float16)vv; ll[0] = (_Float16)(vv - (float)hh[0]);
            vv = v0.y; hh[1] = (_Float16)vv; ll[1] = (_Float16)(vv - (float)hh[1]);
            vv = v0.z; hh[2] = (_Float16)vv; ll[2] = (_Float16)(vv - (float)hh[2]);
            vv = v0.w; hh[3] = (_Float16)vv; ll[3] = (_Float16)(vv - (float)hh[3]);
            vv = v1.x; hh[4] = (_Float16)vv; ll[4] = (_Float16)(vv - (float)hh[4]);
            vv = v1.y; hh[5] = (_Float16)vv; ll[5] = (_Float16)(vv - (float)hh[5]);
            vv = v1.z; hh[6] = (_Float16)vv; ll[6] = (_Float16)(vv - (float)hh[6]);
            vv = v1.w; hh[7] = (_Float16)vv; ll[7] = (_Float16)(vv - (float)hh[7]);
            ah[mt][kh] = hh;
            al[mt][kh] = ll;
        }
    }

    // running top-2 per slot (mt, r): pixel p_local = mt*16 + lk*4 + r
    float b1[2][4], b2[2][4];
    int   i1[2][4];
    #pragma unroll
    for (int mt = 0; mt < 2; ++mt)
        #pragma unroll
        for (int r = 0; r < 4; ++r) { b1[mt][r] = 3.4e38f; b2[mt][r] = 3.4e38f; i1[mt][r] = 0; }

    #pragma unroll 1
    for (int t = 0; t < 8; ++t) {
        const int kbase = t * 128;
        __syncthreads();   // previous panel fully consumed
        {
            const float4* sh = (const float4*)(eh + (size_t)kbase * DDIM);
            const float4* sl = (const float4*)(el + (size_t)kbase * DDIM);
            float4* dh = (float4*)EH8;
            float4* dl = (float4*)EL8;
            #pragma unroll
            for (int i = 0; i < 4; ++i) {
                int G = tid + i * 256;            // 0..1023 granules of 16B
                int code = G >> 3, g = G & 7;
                int sw = g ^ (code & 7);          // XOR granule swizzle
                dh[code * 8 + sw] = sh[G];
                dl[code * 8 + sw] = sl[G];
            }
            if (tid < 128) NRM[tid] = norms[kbase + tid];
        }
        __syncthreads();

        #pragma unroll 1
        for (int c = 0; c < 8; ++c) {
            int code = c * 16 + lx;
            const half8* bh = EH8 + code * 8;
            const half8* bl = EL8 + code * 8;
            int sw0 = lk ^ (code & 7);
            int sw1 = (lk + 4) ^ (code & 7);
            half8 bh0 = bh[sw0], bh1 = bh[sw1];
            half8 bl0 = bl[sw0], bl1 = bl[sw1];

            f32x4 acc0 = {0.f, 0.f, 0.f, 0.f};
            f32x4 acc1 = {0.f, 0.f, 0.f, 0.f};
            acc0 = __builtin_amdgcn_mfma_f32_16x16x32_f16(ah[0][0], bh0, acc0, 0, 0, 0);
            acc1 = __builtin_amdgcn_mfma_f32_16x16x32_f16(ah[1][0], bh0, acc1, 0, 0, 0);
            acc0 = __builtin_amdgcn_mfma_f32_16x16x32_f16(ah[0][1], bh1, acc0, 0, 0, 0);
            acc1 = __builtin_amdgcn_mfma_f32_16x16x32_f16(ah[1][1], bh1, acc1, 0, 0, 0);
            acc0 = __builtin_amdgcn_mfma_f32_16x16x32_f16(ah[0][0], bl0, acc0, 0, 0, 0);
            acc1 = __builtin_amdgcn_mfma_f32_16x16x32_f16(ah[1][0], bl0, acc1, 0, 0, 0);
            acc0 = __builtin_amdgcn_mfma_f32_16x16x32_f16(ah[0][1], bl1, acc0, 0, 0, 0);
            acc1 = __builtin_amdgcn_mfma_f32_16x16x32_f16(ah[1][1], bl1, acc1, 0, 0, 0);
            acc0 = __builtin_amdgcn_mfma_f32_16x16x32_f16(al[0][0], bh0, acc0, 0, 0, 0);
            acc1 = __builtin_amdgcn_mfma_f32_16x16x32_f16(al[1][0], bh0, acc1, 0, 0, 0);
            acc0 = __builtin_amdgcn_mfma_f32_16x16x32_f16(al[0][1], bh1, acc0, 0, 0, 0);
            acc1 = __builtin_amdgcn_mfma_f32_16x16x32_f16(al[1][1], bh1, acc1, 0, 0, 0);

            float nrm = NRM[c * 16 + lx];
            int codeg = kbase + c * 16 + lx;
            #pragma unroll
            for (int r = 0; r < 4; ++r) {
                // C layout [m89]: col = lane&15 (code), row = (lane>>4)*4 + r (pixel)
                float d0 = fmaf(-2.0f, acc0[r], nrm);
                bool lt0 = d0 < b1[0][r];
                b2[0][r] = fminf(b2[0][r], fmaxf(b1[0][r], d0));
                b1[0][r] = fminf(b1[0][r], d0);
                i1[0][r] = lt0 ? codeg : i1[0][r];
                float d1 = fmaf(-2.0f, acc1[r], nrm);
                bool lt1 = d1 < b1[1][r];
                b2[1][r] = fminf(b2[1][r], fmaxf(b1[1][r], d1));
                b1[1][r] = fminf(b1[1][r], d1);
                i1[1][r] = lt1 ? codeg : i1[1][r];
            }
        }
    }

    // cross-lane per-pixel top-2 merge via LDS scratch (panels now dead)
    __syncthreads();
    float* S  = (float*)(lds_raw + wave * 6528);  // 3 planes of [32][17] floats
    float* SB1 = S, *SI = S + 544, *SB2 = S + 1088;
    #pragma unroll
    for (int mt = 0; mt < 2; ++mt)
        #pragma unroll
        for (int r = 0; r < 4; ++r) {
            int p = mt * 16 + lk * 4 + r;
            SB1[p * 17 + lx] = b1[mt][r];
            SI [p * 17 + lx] = (float)i1[mt][r];
            SB2[p * 17 + lx] = b2[mt][r];
        }
    __syncthreads();

    if (lane < 32) {
        float gb1 = 3.4e38f, gb2 = 3.4e38f;
        int gi1 = KCODE;
        #pragma unroll
        for (int j = 0; j < 16; ++j) {
            float cb1 = SB1[lane * 17 + j];
            int   ci1 = (int)SI[lane * 17 + j];
            float cb2 = SB2[lane * 17 + j];
            if (cb1 < gb1 || (cb1 == gb1 && ci1 < gi1)) {
                gb2 = fminf(gb1, cb2); gb1 = cb1; gi1 = ci1;
            } else {
                gb2 = fminf(gb2, cb1);
            }
        }
        int pixel = pixbase + lane;
        idxf[pixel] = (float)gi1;
        if (gb2 - gb1 < EPS2) {
            int slot = atomicAdd(fixcount, 1);
            if (slot < FIXCAP) fixlist[slot] = pixel;
        }
    }
}

// ---------- exact fp32 rescan for flagged pixels (first-min-wins) ----------
__global__ __launch_bounds__(64) void vq_fixup(
        const float* __restrict__ x, const float* __restrict__ embT,
        const float* __restrict__ norms, const int* __restrict__ fixlist,
        const int* __restrict__ fixcount, float* __restrict__ idxf) {
    int b = blockIdx.x;
    int cnt = *fixcount;
    if (b >= cnt) return;
    int pixel = fixlist[b];
    int lane = threadIdx.x;

    float xr[64];
    const float4* x4 = (const float4*)(x + (size_t)pixel * DDIM);
    #pragma unroll
    for (int j = 0; j < 16; ++j) {
        float4 v = x4[j];
        xr[j * 4] = v.x; xr[j * 4 + 1] = v.y; xr[j * 4 + 2] = v.z; xr[j * 4 + 3] = v.w;
    }
    float bd = 3.4e38f;
    int bi = 0;
    #pragma unroll 1
    for (int c = 0; c < 16; ++c) {
        int k = lane * 16 + c;               // per-lane ascending idx
        const float4* e4 = (const float4*)(embT + (size_t)k * DDIM);
        float a0 = 0.f, a1 = 0.f, a2 = 0.f, a3 = 0.f;
        #pragma unroll
        for (int j = 0; j < 16; ++j) {
            float4 ev = e4[j];
            a0 = fmaf(xr[j * 4],     ev.x, a0);
            a1 = fmaf(xr[j * 4 + 1], ev.y, a1);
            a2 = fmaf(xr[j * 4 + 2], ev.z, a2);
            a3 = fmaf(xr[j * 4 + 3], ev.w, a3);
        }
        float dd = fmaf(-2.0f, (a0 + a1) + (a2 + a3), norms[k]);
        if (dd < bd) { bd = dd; bi = k; }
    }
    #pragma unroll
    for (int m = 1; m < 64; m <<= 1) {       // lex-min (dist, idx) across 64 lanes
        float od = __shfl_xor(bd, m, 64);
        int   oi = __shfl_xor(bi, m, 64);
        if (od < bd || (od == bd && oi < bi)) { bd = od; bi = oi; }
    }
    if (lane == 0) idxf[pixel] = (float)bi;
}

// ---------- gather quantized + per-block loss partials + histogram ----------
__global__ __launch_bounds__(256) void vq_gather_loss(
        const float* __restrict__ x, const float* __restrict__ embT,
        const float* __restrict__ idxf, float* __restrict__ q,
        float* __restrict__ lossp, int* __restrict__ hist) {
    __shared__ float red[256];
    int i = blockIdx.x * 256 + threadIdx.x;   // over 2097152 float4 units
    int n = i >> 4;
    int j = i & 15;
    int idx = (int)idxf[n];
    if (j == 0) atomicAdd(&hist[idx], 1);
    float4 e4 = ((const float4*)embT)[idx * 16 + j];
    float4 xv = ((const float4*)x)[i];
    ((float4*)q)[i] = e4;
    float dx = e4.x - xv.x, dy = e4.y - xv.y, dz = e4.z - xv.z, dw = e4.w - xv.w;
    red[threadIdx.x] = dx*dx + dy*dy + dz*dz + dw*dw;
    __syncthreads();
    for (int st = 128; st > 0; st >>= 1) {
        if (threadIdx.x < st) red[threadIdx.x] += red[threadIdx.x + st];
        __syncthreads();
    }
    if (threadIdx.x == 0) lossp[blockIdx.x] = red[0];
}

// ---------- one-hot fill: flat 16B-aligned REGULAR stores (A/B: no nt) ------
// enc base byte ≡ 8 (mod 16) -> enc+2 is 16B aligned. Head/tail 2 floats
// handled by one thread. Aligned float4 segments: 33554431.
__global__ __launch_bounds__(256) void vq_fill(const float* __restrict__ idxf,
                                               float* __restrict__ enc) {
    const long long NSEG = 33554431LL;
    f32x4* base = (f32x4*)(enc + 2);
    long long t0 = (long long)blockIdx.x * 256 + threadIdx.x;
    long long stride = (long long)gridDim.x * 256;
    for (long long s = t0; s < NSEG; s += stride) {
        long long f = 2 + 4 * s;              // flat float index into enc
        int n = (int)(f >> 10);
        int k = (int)(f & 1023);
        int idx0 = (int)idxf[n];
        f32x4 v;
        if (k <= 1020) {
            v.x = (k     == idx0) ? 1.f : 0.f;
            v.y = (k + 1 == idx0) ? 1.f : 0.f;
            v.z = (k + 2 == idx0) ? 1.f : 0.f;
            v.w = (k + 3 == idx0) ? 1.f : 0.f;
        } else {                              // k == 1022: crosses row boundary
            int idx1 = (int)idxf[n + 1];
            v.x = (1022 == idx0) ? 1.f : 0.f;
            v.y = (1023 == idx0) ? 1.f : 0.f;
            v.z = (0    == idx1) ? 1.f : 0.f;
            v.w = (1    == idx1) ? 1.f : 0.f;
        }
        base[s] = v;                          // plain store (L2 write-back)
    }
    if (t0 == 0) {
        int idx0 = (int)idxf[0];
        enc[0] = (idx0 == 0) ? 1.f : 0.f;
        enc[1] = (idx0 == 1) ? 1.f : 0.f;
        int idxL = (int)idxf[NPIX - 1];
        enc[134217726] = (idxL == 1022) ? 1.f : 0.f;
        enc[134217727] = (idxL == 1023) ? 1.f : 0.f;
    }
}

// ---------- finalize: loss sum + perplexity ----------
__global__ void vq_final(const float* __restrict__ lossp, const int* __restrict__ hist,
                         float* __restrict__ out_loss, float* __restrict__ out_perp) {
    __shared__ double red[256];
    int tid = threadIdx.x;
    double s = 0.0;
    for (int i = tid; i < 8192; i += 256) s += (double)lossp[i];
    red[tid] = s;
    __syncthreads();
    for (int st = 128; st > 0; st >>= 1) {
        if (tid < st) red[tid] += red[tid + st];
        __syncthreads();
    }
    if (tid == 0)
        *out_loss = (float)((double)BETA * red[0] / (double)((size_t)NPIX * DDIM));
    __syncthreads();

    double e = 0.0;
    for (int i = tid; i < KCODE; i += 256) {
        float p = (float)hist[i] / (float)NPIX;
        e += (double)(p * logf(p + 1e-10f));
    }
    red[tid] = e;
    __syncthreads();
    for (int st = 128; st > 0; st >>= 1) {
        if (tid < st) red[tid] += red[tid + st];
        __syncthreads();
    }
    if (tid == 0) *out_perp = expf((float)(-red[0]));
}

extern "C" void kernel_launch(void* const* d_in, const int* in_sizes, int n_in,
                              void* d_out, int out_size, void* d_ws, size_t ws_size,
                              hipStream_t stream) {
    const float* x   = (const float*)d_in[0];
    const float* emb = (const float*)d_in[1];
    float* out = (float*)d_out;

    char* ws = (char*)d_ws;
    float* lossp = (float*)ws;              // 8192 floats
    int*   hist  = (int*)(ws + 32768);      // 1024 ints
    float* norms = (float*)(ws + 36864);    // 1024 floats
    float* embT  = (float*)(ws + 40960);    // 65536 floats

    float* q      = out + Q_OFF;
    float* o_loss = out + LOSS_OFF;
    float* o_perp = out + PERP_OFF;
    float* enc    = out + ENC_OFF;
    float* idxf   = out + IDX_OFF;

    // scratch inside the enc region (fully overwritten by vq_fill afterwards)
    __half* eh    = (__half*)(enc + EHT_F);
    __half* el    = (__half*)(enc + ELT_F);
    int* fixlist  = (int*)(enc + FIXLIST_I);
    int* fixcount = (int*)(enc + FIXCOUNT_I);

    (void)hipMemsetAsync(ws + 32768, 0, 4096, stream);          // hist
    (void)hipMemsetAsync((void*)fixcount, 0, 4, stream);        // fix-up counter

    vq_prep<<<256, 256, 0, stream>>>(emb, embT, eh, el);
    vq_norms<<<4, 256, 0, stream>>>(emb, norms);
    vq_argmin_mfma<<<NPIX / 128, 256, 0, stream>>>(x, eh, el, norms, idxf,
                                                   fixlist, fixcount);
    vq_fixup<<<FIXCAP, 64, 0, stream>>>(x, embT, norms, fixlist, fixcount, idxf);
    vq_gather_loss<<<8192, 256, 0, stream>>>(x, embT, idxf, q, lossp, hist);
    vq_fill<<<4096, 256, 0, stream>>>(idxf, enc);
    vq_final<<<1, 256, 0, stream>>>(lossp, hist, o_loss, o_perp);
}